// Round 1
// baseline (344.423 us; speedup 1.0000x reference)
//
#include <hip/hip_runtime.h>
#include <stdint.h>

typedef __attribute__((ext_vector_type(4))) float f32x4;
typedef __attribute__((ext_vector_type(8))) short s16x8;
typedef unsigned short u16;
typedef unsigned int u32;

#define B_ 4
#define C_ 256
#define O_ 256
#define H_ 96
#define W_ 96
#define HW_ (H_*W_)      /* 9216 */
#define M_ (B_*HW_)      /* 36864 */

static __device__ __forceinline__ float bf2f(u16 u){
    union { u32 u; float f; } x; x.u = ((u32)u) << 16; return x.f;
}
static __device__ __forceinline__ u16 f2bf(float f){
    union { float f; u32 u; } x; x.f = f;
    u32 u = x.u;
    u32 r = (u + 0x7fffu + ((u >> 16) & 1u)) >> 16;
    return (u16)r;
}

// ---------------------------------------------------------------------------
// Kernel 1: transpose x [B,C,H,W] f32 -> xT [B,H,W,C] bf16
// ---------------------------------------------------------------------------
__global__ __launch_bounds__(256) void transpose_x(const float* __restrict__ x,
                                                   u16* __restrict__ xT)
{
    __shared__ float t[32][33];
    int tid = threadIdx.x;
    int tx = tid & 31, ty = tid >> 5;          // 32 x 8
    int bi = blockIdx.x;
    int w0 = (bi % 3) * 32;
    int c0 = ((bi / 3) % 8) * 32;
    int bh = bi / 24;                           // b*H + h  (0..383)
    int b = bh / H_, h = bh - b * H_;
    #pragma unroll
    for (int r = 0; r < 4; ++r){
        int c = c0 + ty + r * 8;
        t[ty + r * 8][tx] = x[(size_t)(b * C_ + c) * HW_ + h * W_ + w0 + tx];
    }
    __syncthreads();
    #pragma unroll
    for (int r = 0; r < 4; ++r){
        int w = w0 + ty + r * 8;
        xT[((size_t)(b * H_ + h) * W_ + w) * C_ + c0 + tx] = f2bf(t[tx][ty + r * 8]);
    }
}

// ---------------------------------------------------------------------------
// Kernel 2: pack weight [O,C,3,3] f32 -> W3 bf16, layout:
//   kidx = tap*256 + c  (tap = ky*3+kx)
//   flat u16 index = (kidx>>3)*2048 + o*8 + (kidx&7)
// so a b-fragment load (lane l, col o, k-chunk g) is one contiguous 16B read.
// ---------------------------------------------------------------------------
__global__ __launch_bounds__(256) void pack_w(const float* __restrict__ wt,
                                              u16* __restrict__ w3)
{
    int n = blockIdx.x * 256 + threadIdx.x;     // < 589824 = 256*256*9
    int o = n / 2304;
    int rem = n - o * 2304;
    int c = rem / 9;
    int tap = rem - c * 9;
    int kidx = tap * 256 + c;
    w3[(size_t)(kidx >> 3) * 2048 + o * 8 + (kidx & 7)] = f2bf(wt[n]);
}

// ---------------------------------------------------------------------------
// Kernel 3: main deformable-conv implicit GEMM.
// Grid 576 blocks (BM=64 pixels), 256 threads = 4 waves, each wave owns a
// 64x64 output sub-tile (wave w -> cols [w*64, w*64+64)).
// Per tap: gather A-tile (64 px x 256 ch) bf16 into XOR-swizzled LDS, then
// 8 K-steps of mfma_f32_16x16x32_bf16 (4 m-frags x 4 n-frags).
// ---------------------------------------------------------------------------
__global__ __launch_bounds__(256, 2) void dcn_main(
    const float* __restrict__ off, const float* __restrict__ msk,
    const u16* __restrict__ xT, const u16* __restrict__ w3,
    float* __restrict__ convOut, float* __restrict__ stats)
{
    __shared__ u16 A[64 * 256];   // 32 KB, XOR-swizzled rows of 512B
    int tid = threadIdx.x;
    int lane = tid & 63;
    int wv = tid >> 6;            // 0..3 : n-block
    int m0 = blockIdx.x * 64;
    int b = m0 / HW_;

    f32x4 acc[4][4];
    #pragma unroll
    for (int i = 0; i < 4; ++i)
        #pragma unroll
        for (int q = 0; q < 4; ++q)
            acc[i][q] = (f32x4){0.f, 0.f, 0.f, 0.f};

    // gather assignment: 4 threads per pixel, 64 channels each
    int p = tid >> 2;             // pixel 0..63
    int m = m0 + p;
    int hw = m - b * HW_;
    int h = hw / W_, w = hw - h * W_;
    int c0 = (tid & 3) * 64;

    for (int tap = 0; tap < 9; ++tap){
        __syncthreads();  // previous tap's LDS reads complete
        // ---- gather this tap's A-tile ----
        float dy = off[(size_t)(b * 18 + 2 * tap) * HW_ + hw];
        float dx = off[(size_t)(b * 18 + 2 * tap + 1) * HW_ + hw];
        float mk = msk[(size_t)(b * 9 + tap) * HW_ + hw];
        float py = (float)(h + tap / 3 - 1) + dy;
        float px = (float)(w + tap % 3 - 1) + dx;
        float fy = floorf(py), fx = floorf(px);
        float wy = py - fy, wx = px - fx;
        int y0 = (int)fy, x0 = (int)fx;
        int y1 = y0 + 1, x1 = x0 + 1;
        float w00 = (1.f - wy) * (1.f - wx) * mk;
        float w01 = (1.f - wy) * wx * mk;
        float w10 = wy * (1.f - wx) * mk;
        float w11 = wy * wx * mk;
        if (y0 < 0 || y0 >= H_) { w00 = 0.f; w01 = 0.f; }
        if (y1 < 0 || y1 >= H_) { w10 = 0.f; w11 = 0.f; }
        if (x0 < 0 || x0 >= W_) { w00 = 0.f; w10 = 0.f; }
        if (x1 < 0 || x1 >= W_) { w01 = 0.f; w11 = 0.f; }
        int cy0 = min(max(y0, 0), H_ - 1), cy1 = min(max(y1, 0), H_ - 1);
        int cx0 = min(max(x0, 0), W_ - 1), cx1 = min(max(x1, 0), W_ - 1);
        size_t rb = (size_t)b * HW_ * C_;
        const u16* r00 = xT + rb + ((size_t)cy0 * W_ + cx0) * C_;
        const u16* r01 = xT + rb + ((size_t)cy0 * W_ + cx1) * C_;
        const u16* r10 = xT + rb + ((size_t)cy1 * W_ + cx0) * C_;
        const u16* r11 = xT + rb + ((size_t)cy1 * W_ + cx1) * C_;
        #pragma unroll
        for (int i = 0; i < 8; ++i){
            int c = c0 + i * 8;
            s16x8 v00 = *(const s16x8*)(r00 + c);
            s16x8 v01 = *(const s16x8*)(r01 + c);
            s16x8 v10 = *(const s16x8*)(r10 + c);
            s16x8 v11 = *(const s16x8*)(r11 + c);
            s16x8 outv;
            #pragma unroll
            for (int j = 0; j < 8; ++j){
                float f = w00 * bf2f((u16)v00[j]) + w01 * bf2f((u16)v01[j])
                        + w10 * bf2f((u16)v10[j]) + w11 * bf2f((u16)v11[j]);
                outv[j] = (short)f2bf(f);
            }
            u32 boff = (u32)(p * 512 + c * 2);
            boff ^= (u32)((p & 7) << 4);
            *(s16x8*)((char*)A + boff) = outv;
        }
        __syncthreads();
        // ---- MFMA over this tap's K=256 chunk ----
        int g = lane >> 4;
        #pragma unroll
        for (int step = 0; step < 8; ++step){
            s16x8 a[4];
            int akb = (step * 32 + g * 8) * 2;
            #pragma unroll
            for (int i = 0; i < 4; ++i){
                int r = i * 16 + (lane & 15);
                u32 boff = (u32)(r * 512 + akb) ^ (u32)((r & 7) << 4);
                a[i] = *(const s16x8*)((const char*)A + boff);
            }
            const u16* wrow = w3 + (size_t)(tap * 32 + step * 4 + g) * 2048
                            + (wv * 64 + (lane & 15)) * 8;
            s16x8 bq[4];
            #pragma unroll
            for (int q = 0; q < 4; ++q)
                bq[q] = *(const s16x8*)(wrow + q * 128);
            #pragma unroll
            for (int i = 0; i < 4; ++i)
                #pragma unroll
                for (int q = 0; q < 4; ++q)
                    acc[i][q] = __builtin_amdgcn_mfma_f32_16x16x32_bf16(
                        a[i], bq[q], acc[i][q], 0, 0, 0);
        }
    }

    // ---- epilogue: store conv f32 [m][o], accumulate GN partial stats ----
    int rbase = (lane >> 4) * 4;
    int cbase = wv * 64 + (lane & 15);
    float s0 = 0.f, s20 = 0.f, s1 = 0.f, s21 = 0.f;
    #pragma unroll
    for (int i = 0; i < 4; ++i){
        #pragma unroll
        for (int q = 0; q < 4; ++q){
            int oc = cbase + q * 16;
            #pragma unroll
            for (int j = 0; j < 4; ++j){
                float v = acc[i][q][j];
                int mr = m0 + i * 16 + rbase + j;
                convOut[(size_t)mr * 256 + oc] = v;
                if (q < 2) { s0 += v; s20 += v * v; }
                else       { s1 += v; s21 += v * v; }
            }
        }
    }
    #pragma unroll
    for (int d = 32; d; d >>= 1){
        s0  += __shfl_xor(s0, d, 64);
        s20 += __shfl_xor(s20, d, 64);
        s1  += __shfl_xor(s1, d, 64);
        s21 += __shfl_xor(s21, d, 64);
    }
    if (lane == 0){
        int g0 = 2 * wv, g1 = 2 * wv + 1;
        atomicAdd(&stats[(b * 8 + g0) * 2 + 0], s0);
        atomicAdd(&stats[(b * 8 + g0) * 2 + 1], s20);
        atomicAdd(&stats[(b * 8 + g1) * 2 + 0], s1);
        atomicAdd(&stats[(b * 8 + g1) * 2 + 1], s21);
    }
}

// ---------------------------------------------------------------------------
// Kernel 4: GroupNorm(8) + ReLU, transposing [m][o] -> [b,o,h,w]
// ---------------------------------------------------------------------------
__global__ __launch_bounds__(256) void gn_final(
    const float* __restrict__ convOut, const float* __restrict__ stats,
    const float* __restrict__ gamma, const float* __restrict__ beta,
    float* __restrict__ out)
{
    __shared__ float t[64][257];
    int tid = threadIdx.x;
    int m0 = blockIdx.x * 64;
    int b = m0 / HW_;
    const f32x4* src = (const f32x4*)(convOut + (size_t)m0 * 256);
    #pragma unroll
    for (int it = 0; it < 16; ++it){
        int idx = it * 256 + tid;
        int r = idx >> 6;
        int c4 = idx & 63;
        f32x4 v = src[(size_t)r * 64 + c4];
        t[r][c4 * 4 + 0] = v[0];
        t[r][c4 * 4 + 1] = v[1];
        t[r][c4 * 4 + 2] = v[2];
        t[r][c4 * 4 + 3] = v[3];
    }
    __syncthreads();
    int lanem = tid & 63;
    int hw = (m0 - b * HW_) + lanem;
    float* dst = out + (size_t)b * O_ * HW_ + hw;
    const float invN = 1.f / 294912.f;   // 32 ch * 9216 px
    #pragma unroll 8
    for (int it = 0; it < 64; ++it){
        int o = it * 4 + (tid >> 6);
        int gidx = (b * 8 + (o >> 5)) * 2;
        float sm = stats[gidx + 0];
        float sq = stats[gidx + 1];
        float mu = sm * invN;
        float var = sq * invN - mu * mu;
        float inv = rsqrtf(var + 1e-5f);
        float sc = gamma[o] * inv;
        float sh = beta[o] - mu * sc;
        float v = t[lanem][o];
        dst[(size_t)o * HW_] = fmaxf(v * sc + sh, 0.f);
    }
}

// ---------------------------------------------------------------------------
extern "C" void kernel_launch(void* const* d_in, const int* in_sizes, int n_in,
                              void* d_out, int out_size, void* d_ws, size_t ws_size,
                              hipStream_t stream)
{
    const float* x     = (const float*)d_in[0];
    const float* off   = (const float*)d_in[1];
    const float* msk   = (const float*)d_in[2];
    const float* wt    = (const float*)d_in[3];
    const float* gamma = (const float*)d_in[4];
    const float* beta  = (const float*)d_in[5];
    float* out = (float*)d_out;

    char* ws = (char*)d_ws;
    u16*   xT      = (u16*)ws;                       // 18,874,368 B
    u16*   w3      = (u16*)(ws + 18874368);          //  1,179,648 B
    float* convOut = (float*)(ws + 20054016);        // 37,748,736 B
    float* stats   = (float*)(ws + 57802752);        //        256 B

    hipMemsetAsync(stats, 0, 256, stream);
    hipLaunchKernelGGL(transpose_x, dim3(9216), dim3(256), 0, stream, x, xT);
    hipLaunchKernelGGL(pack_w,      dim3(2304), dim3(256), 0, stream, wt, w3);
    hipLaunchKernelGGL(dcn_main,    dim3(576),  dim3(256), 0, stream,
                       off, msk, xT, w3, convOut, stats);
    hipLaunchKernelGGL(gn_final,    dim3(576),  dim3(256), 0, stream,
                       convOut, stats, gamma, beta, out);
}

// Round 2
// 214.060 us; speedup vs baseline: 1.6090x; 1.6090x over previous
//
#include <hip/hip_runtime.h>
#include <stdint.h>

typedef __attribute__((ext_vector_type(4))) float f32x4;
typedef __attribute__((ext_vector_type(8))) short s16x8;
typedef unsigned short u16;
typedef unsigned int u32;

#define B_ 4
#define C_ 256
#define O_ 256
#define H_ 96
#define W_ 96
#define HW_ (H_*W_)      /* 9216 */
#define M_ (B_*HW_)      /* 36864 */

static __device__ __forceinline__ float bf2f(u16 u){
    union { u32 u; float f; } x; x.u = ((u32)u) << 16; return x.f;
}
static __device__ __forceinline__ u16 f2bf(float f){
    union { float f; u32 u; } x; x.f = f;
    u32 u = x.u;
    u32 r = (u + 0x7fffu + ((u >> 16) & 1u)) >> 16;
    return (u16)r;
}

// ---------------------------------------------------------------------------
// Kernel 1: transpose x [B,C,H,W] f32 -> xT [B,H,W,C] bf16
// ---------------------------------------------------------------------------
__global__ __launch_bounds__(256) void transpose_x(const float* __restrict__ x,
                                                   u16* __restrict__ xT)
{
    __shared__ float t[32][33];
    int tid = threadIdx.x;
    int tx = tid & 31, ty = tid >> 5;          // 32 x 8
    int bi = blockIdx.x;
    int w0 = (bi % 3) * 32;
    int c0 = ((bi / 3) % 8) * 32;
    int bh = bi / 24;                           // b*H + h  (0..383)
    int b = bh / H_, h = bh - b * H_;
    #pragma unroll
    for (int r = 0; r < 4; ++r){
        int c = c0 + ty + r * 8;
        t[ty + r * 8][tx] = x[(size_t)(b * C_ + c) * HW_ + h * W_ + w0 + tx];
    }
    __syncthreads();
    #pragma unroll
    for (int r = 0; r < 4; ++r){
        int w = w0 + ty + r * 8;
        xT[((size_t)(b * H_ + h) * W_ + w) * C_ + c0 + tx] = f2bf(t[tx][ty + r * 8]);
    }
}

// ---------------------------------------------------------------------------
// Kernel 2: pack weight [O,C,3,3] f32 -> W3 bf16, layout:
//   kidx = tap*256 + c  (tap = ky*3+kx)
//   flat u16 index = (kidx>>3)*2048 + o*8 + (kidx&7)
// ---------------------------------------------------------------------------
__global__ __launch_bounds__(256) void pack_w(const float* __restrict__ wt,
                                              u16* __restrict__ w3)
{
    int n = blockIdx.x * 256 + threadIdx.x;     // < 589824 = 256*256*9
    int o = n / 2304;
    int rem = n - o * 2304;
    int c = rem / 9;
    int tap = rem - c * 9;
    int kidx = tap * 256 + c;
    w3[(size_t)(kidx >> 3) * 2048 + o * 8 + (kidx & 7)] = f2bf(wt[n]);
}

// ---------------------------------------------------------------------------
// Kernel 3: main deformable-conv implicit GEMM.
// 576 blocks; block = one 8x8 pixel patch (12x12 patches per image, 4 images).
// XCD-contiguous tile assignment: tile = (bid%8)*72 + bid/8, raster order ->
// each XCD owns 72 consecutive patches = half of one image (~2.4 MB of xT),
// which fits its private 4 MB L2.
// 256 threads = 4 waves, wave w -> output cols [w*64, w*64+64).
// Per tap: gather 64px x 256ch bf16 A-tile into XOR-swizzled LDS, then
// 8 K-steps of mfma_f32_16x16x32_bf16 (4 m-frags x 4 n-frags).
// ---------------------------------------------------------------------------
__global__ __launch_bounds__(256, 2) void dcn_main(
    const float* __restrict__ off, const float* __restrict__ msk,
    const u16* __restrict__ xT, const u16* __restrict__ w3,
    float* __restrict__ convOut, float* __restrict__ stats)
{
    __shared__ u16 A[64 * 256];   // 32 KB, XOR-swizzled rows of 512B
    int tid = threadIdx.x;
    int lane = tid & 63;
    int wv = tid >> 6;            // 0..3 : n-block

    // ---- tile -> (b, patch) with XCD-contiguous assignment ----
    int bid = blockIdx.x;
    int tile = (bid & 7) * 72 + (bid >> 3);     // 576 = 8 * 72, bijective
    int b = tile / 144;
    int t = tile - b * 144;
    int ty_ = t / 12;
    int tx_ = t - ty_ * 12;
    int py0 = ty_ * 8;
    int px0 = tx_ * 8;

    f32x4 acc[4][4];
    #pragma unroll
    for (int i = 0; i < 4; ++i)
        #pragma unroll
        for (int q = 0; q < 4; ++q)
            acc[i][q] = (f32x4){0.f, 0.f, 0.f, 0.f};

    // gather assignment: 4 threads per pixel, 64 channels each
    int p = tid >> 2;             // pixel 0..63 within patch
    int h = py0 + (p >> 3);
    int w = px0 + (p & 7);
    int hw = h * W_ + w;
    int c0 = (tid & 3) * 64;

    for (int tap = 0; tap < 9; ++tap){
        __syncthreads();  // previous tap's LDS reads complete
        // ---- gather this tap's A-tile ----
        float dy = off[(size_t)(b * 18 + 2 * tap) * HW_ + hw];
        float dx = off[(size_t)(b * 18 + 2 * tap + 1) * HW_ + hw];
        float mk = msk[(size_t)(b * 9 + tap) * HW_ + hw];
        float py = (float)(h + tap / 3 - 1) + dy;
        float px = (float)(w + tap % 3 - 1) + dx;
        float fy = floorf(py), fx = floorf(px);
        float wy = py - fy, wx = px - fx;
        int y0 = (int)fy, x0 = (int)fx;
        int y1 = y0 + 1, x1 = x0 + 1;
        float w00 = (1.f - wy) * (1.f - wx) * mk;
        float w01 = (1.f - wy) * wx * mk;
        float w10 = wy * (1.f - wx) * mk;
        float w11 = wy * wx * mk;
        if (y0 < 0 || y0 >= H_) { w00 = 0.f; w01 = 0.f; }
        if (y1 < 0 || y1 >= H_) { w10 = 0.f; w11 = 0.f; }
        if (x0 < 0 || x0 >= W_) { w00 = 0.f; w10 = 0.f; }
        if (x1 < 0 || x1 >= W_) { w01 = 0.f; w11 = 0.f; }
        int cy0 = min(max(y0, 0), H_ - 1), cy1 = min(max(y1, 0), H_ - 1);
        int cx0 = min(max(x0, 0), W_ - 1), cx1 = min(max(x1, 0), W_ - 1);
        size_t rb = (size_t)b * HW_ * C_;
        const u16* r00 = xT + rb + ((size_t)cy0 * W_ + cx0) * C_;
        const u16* r01 = xT + rb + ((size_t)cy0 * W_ + cx1) * C_;
        const u16* r10 = xT + rb + ((size_t)cy1 * W_ + cx0) * C_;
        const u16* r11 = xT + rb + ((size_t)cy1 * W_ + cx1) * C_;
        #pragma unroll
        for (int i = 0; i < 8; ++i){
            int c = c0 + i * 8;
            s16x8 v00 = *(const s16x8*)(r00 + c);
            s16x8 v01 = *(const s16x8*)(r01 + c);
            s16x8 v10 = *(const s16x8*)(r10 + c);
            s16x8 v11 = *(const s16x8*)(r11 + c);
            s16x8 outv;
            #pragma unroll
            for (int j = 0; j < 8; ++j){
                float f = w00 * bf2f((u16)v00[j]) + w01 * bf2f((u16)v01[j])
                        + w10 * bf2f((u16)v10[j]) + w11 * bf2f((u16)v11[j]);
                outv[j] = (short)f2bf(f);
            }
            u32 boff = (u32)(p * 512 + c * 2);
            boff ^= (u32)((p & 7) << 4);
            *(s16x8*)((char*)A + boff) = outv;
        }
        __syncthreads();
        // ---- MFMA over this tap's K=256 chunk ----
        int g = lane >> 4;
        #pragma unroll
        for (int step = 0; step < 8; ++step){
            s16x8 a[4];
            int akb = (step * 32 + g * 8) * 2;
            #pragma unroll
            for (int i = 0; i < 4; ++i){
                int r = i * 16 + (lane & 15);
                u32 boff = (u32)(r * 512 + akb) ^ (u32)((r & 7) << 4);
                a[i] = *(const s16x8*)((const char*)A + boff);
            }
            const u16* wrow = w3 + (size_t)(tap * 32 + step * 4 + g) * 2048
                            + (wv * 64 + (lane & 15)) * 8;
            s16x8 bq[4];
            #pragma unroll
            for (int q = 0; q < 4; ++q)
                bq[q] = *(const s16x8*)(wrow + q * 128);
            #pragma unroll
            for (int i = 0; i < 4; ++i)
                #pragma unroll
                for (int q = 0; q < 4; ++q)
                    acc[i][q] = __builtin_amdgcn_mfma_f32_16x16x32_bf16(
                        a[i], bq[q], acc[i][q], 0, 0, 0);
        }
    }

    // ---- epilogue: store conv f32 at global [m][o], accumulate GN stats ----
    int rbase = (lane >> 4) * 4;
    int cbase = wv * 64 + (lane & 15);
    float s0 = 0.f, s20 = 0.f, s1 = 0.f, s21 = 0.f;
    size_t mbase = (size_t)b * HW_;
    #pragma unroll
    for (int i = 0; i < 4; ++i){
        #pragma unroll
        for (int q = 0; q < 4; ++q){
            int oc = cbase + q * 16;
            #pragma unroll
            for (int j = 0; j < 4; ++j){
                float v = acc[i][q][j];
                int pp = i * 16 + rbase + j;              // pixel in patch
                int mr_hw = (py0 + (pp >> 3)) * W_ + px0 + (pp & 7);
                convOut[(mbase + mr_hw) * 256 + oc] = v;
                if (q < 2) { s0 += v; s20 += v * v; }
                else       { s1 += v; s21 += v * v; }
            }
        }
    }
    #pragma unroll
    for (int d = 32; d; d >>= 1){
        s0  += __shfl_xor(s0, d, 64);
        s20 += __shfl_xor(s20, d, 64);
        s1  += __shfl_xor(s1, d, 64);
        s21 += __shfl_xor(s21, d, 64);
    }
    if (lane == 0){
        int g0 = 2 * wv, g1 = 2 * wv + 1;
        atomicAdd(&stats[(b * 8 + g0) * 2 + 0], s0);
        atomicAdd(&stats[(b * 8 + g0) * 2 + 1], s20);
        atomicAdd(&stats[(b * 8 + g1) * 2 + 0], s1);
        atomicAdd(&stats[(b * 8 + g1) * 2 + 1], s21);
    }
}

// ---------------------------------------------------------------------------
// Kernel 4: GroupNorm(8) + ReLU, transposing [m][o] -> [b,o,h,w]
// ---------------------------------------------------------------------------
__global__ __launch_bounds__(256) void gn_final(
    const float* __restrict__ convOut, const float* __restrict__ stats,
    const float* __restrict__ gamma, const float* __restrict__ beta,
    float* __restrict__ out)
{
    __shared__ float t[64][257];
    int tid = threadIdx.x;
    int m0 = blockIdx.x * 64;
    int b = m0 / HW_;
    const f32x4* src = (const f32x4*)(convOut + (size_t)m0 * 256);
    #pragma unroll
    for (int it = 0; it < 16; ++it){
        int idx = it * 256 + tid;
        int r = idx >> 6;
        int c4 = idx & 63;
        f32x4 v = src[(size_t)r * 64 + c4];
        t[r][c4 * 4 + 0] = v[0];
        t[r][c4 * 4 + 1] = v[1];
        t[r][c4 * 4 + 2] = v[2];
        t[r][c4 * 4 + 3] = v[3];
    }
    __syncthreads();
    int lanem = tid & 63;
    int hw = (m0 - b * HW_) + lanem;
    float* dst = out + (size_t)b * O_ * HW_ + hw;
    const float invN = 1.f / 294912.f;   // 32 ch * 9216 px
    #pragma unroll 8
    for (int it = 0; it < 64; ++it){
        int o = it * 4 + (tid >> 6);
        int gidx = (b * 8 + (o >> 5)) * 2;
        float sm = stats[gidx + 0];
        float sq = stats[gidx + 1];
        float mu = sm * invN;
        float var = sq * invN - mu * mu;
        float inv = rsqrtf(var + 1e-5f);
        float sc = gamma[o] * inv;
        float sh = beta[o] - mu * sc;
        float v = t[lanem][o];
        dst[(size_t)o * HW_] = fmaxf(v * sc + sh, 0.f);
    }
}

// ---------------------------------------------------------------------------
extern "C" void kernel_launch(void* const* d_in, const int* in_sizes, int n_in,
                              void* d_out, int out_size, void* d_ws, size_t ws_size,
                              hipStream_t stream)
{
    const float* x     = (const float*)d_in[0];
    const float* off   = (const float*)d_in[1];
    const float* msk   = (const float*)d_in[2];
    const float* wt    = (const float*)d_in[3];
    const float* gamma = (const float*)d_in[4];
    const float* beta  = (const float*)d_in[5];
    float* out = (float*)d_out;

    char* ws = (char*)d_ws;
    u16*   xT      = (u16*)ws;                       // 18,874,368 B
    u16*   w3      = (u16*)(ws + 18874368);          //  1,179,648 B
    float* convOut = (float*)(ws + 20054016);        // 37,748,736 B
    float* stats   = (float*)(ws + 57802752);        //        256 B

    hipMemsetAsync(stats, 0, 256, stream);
    hipLaunchKernelGGL(transpose_x, dim3(9216), dim3(256), 0, stream, x, xT);
    hipLaunchKernelGGL(pack_w,      dim3(2304), dim3(256), 0, stream, wt, w3);
    hipLaunchKernelGGL(dcn_main,    dim3(576),  dim3(256), 0, stream,
                       off, msk, xT, w3, convOut, stats);
    hipLaunchKernelGGL(gn_final,    dim3(576),  dim3(256), 0, stream,
                       convOut, stats, gamma, beta, out);
}